// Round 5
// baseline (70134.027 us; speedup 1.0000x reference)
//
#include <hip/hip_runtime.h>
#include <hip/hip_bf16.h>

#define HDIM 96
#define G4   384
#define LSEQ 32768
#define BATCH 8

__device__ __forceinline__ float RDL(float v, int l) {
    return __uint_as_float(__builtin_amdgcn_readlane(__float_as_uint(v), l));
}
__device__ __forceinline__ float sigm_(float x) { return 1.f / (1.f + __expf(-x)); }
__device__ __forceinline__ float tanh_(float x) { return 2.f / (1.f + __expf(-2.f * x)) - 1.f; }

// 24 named float4 pairs per thread; loads pinned via empty inline asm.
// amdgpu_waves_per_eu(1,1) on the scan kernels gives the allocator a 512-VGPR
// budget (1 wave/EU) so the weights can actually stay register-resident.
#define W24(F) F(0) F(1) F(2) F(3) F(4) F(5) F(6) F(7) F(8) F(9) F(10) F(11) \
               F(12) F(13) F(14) F(15) F(16) F(17) F(18) F(19) F(20) F(21) F(22) F(23)
#define WDECL(n) float4 w0_##n, w1_##n;
#define WLOAD(n) w0_##n = W0p[n]; w1_##n = W1p[n];
#define WPIN(n) asm volatile("" : "+v"(w0_##n.x), "+v"(w0_##n.y), "+v"(w0_##n.z), "+v"(w0_##n.w), \
                                  "+v"(w1_##n.x), "+v"(w1_##n.y), "+v"(w1_##n.z), "+v"(w1_##n.w));

// matvec over h[0..63] (hA, lane-indexed) and h[64..95] (hB, lanes 0-31)
#define MVA(n) { \
    float ha0_ = RDL(hA, 4*n+0), ha1_ = RDL(hA, 4*n+1), ha2_ = RDL(hA, 4*n+2), ha3_ = RDL(hA, 4*n+3); \
    a0 = fmaf(w0_##n.x, ha0_, a0); a1 = fmaf(w1_##n.x, ha0_, a1); \
    b0 = fmaf(w0_##n.y, ha1_, b0); b1 = fmaf(w1_##n.y, ha1_, b1); \
    a0 = fmaf(w0_##n.z, ha2_, a0); a1 = fmaf(w1_##n.z, ha2_, a1); \
    b0 = fmaf(w0_##n.w, ha3_, b0); b1 = fmaf(w1_##n.w, ha3_, b1); }
#define MVB(n) { \
    float hb0_ = RDL(hB, 4*n-64), hb1_ = RDL(hB, 4*n-63), hb2_ = RDL(hB, 4*n-62), hb3_ = RDL(hB, 4*n-61); \
    a0 = fmaf(w0_##n.x, hb0_, a0); a1 = fmaf(w1_##n.x, hb0_, a1); \
    b0 = fmaf(w0_##n.y, hb1_, b0); b1 = fmaf(w1_##n.y, hb1_, b1); \
    a0 = fmaf(w0_##n.z, hb2_, a0); a1 = fmaf(w1_##n.z, hb2_, a1); \
    b0 = fmaf(w0_##n.w, hb3_, b0); b1 = fmaf(w1_##n.w, hb3_, b1); }
#define MV_ALL() \
    MVA(0) MVA(1) MVA(2) MVA(3) MVA(4) MVA(5) MVA(6) MVA(7) \
    MVA(8) MVA(9) MVA(10) MVA(11) MVA(12) MVA(13) MVA(14) MVA(15) \
    MVB(16) MVB(17) MVB(18) MVB(19) MVB(20) MVB(21) MVB(22) MVB(23)

// ---------------------------------------------------------------------------
// Scan: 192 threads (3 waves). Thread tid<96 owns rows (i_e=tid, g_e=tid+192),
// publishes p=sig(i)*tanh(g). Thread 96+e owns (f_e, o_e), publishes (sf,so).
// ONE barrier/step; every wave redundantly updates c,h for the elements it
// broadcasts (hA=h[lane], hB=h[64+lane]) -> h never leaves registers.
// ---------------------------------------------------------------------------
__global__ void __launch_bounds__(192)
__attribute__((amdgpu_waves_per_eu(1, 1)))
lstm_layer0(const float* __restrict__ x,
            const float* __restrict__ Wih,
            const float* __restrict__ Whh,
            const float* __restrict__ bvec,
            const float* __restrict__ h0,
            const float* __restrict__ c0,
            float* __restrict__ hout)
{
    const int bidx = blockIdx.x;
    const int tid  = threadIdx.x;
    const int lane = tid & 63;
    const int wid  = tid >> 6;
    const int r0   = tid;
    const int r1   = tid + 192;

    __shared__ float  p_sh[2][HDIM];
    __shared__ float2 fo_sh[2][HDIM];

    const float4* W0p = reinterpret_cast<const float4*>(Whh + r0 * HDIM);
    const float4* W1p = reinterpret_cast<const float4*>(Whh + r1 * HDIM);
    W24(WDECL)
    W24(WLOAD)
    W24(WPIN)
    const float wi0 = Wih[r0], wi1 = Wih[r1];
    const float bb0 = bvec[r0], bb1 = bvec[r1];

    float hA = h0[lane];
    float hB = (lane < 32) ? h0[64 + lane] : 0.f;
    float cA = c0[lane];
    float cB = (lane < 32) ? c0[64 + lane] : 0.f;

    const float* xb  = x + (size_t)bidx * LSEQ;
    float*       hob = hout + (size_t)bidx * LSEQ * HDIM;
    float xt = xb[0];

#pragma unroll 1
    for (int t = 0; t < LSEQ; ++t) {
        float xnext = (t + 1 < LSEQ) ? xb[t + 1] : 0.f;

        float a0 = fmaf(wi0, xt, bb0), b0 = 0.f;
        float a1 = fmaf(wi1, xt, bb1), b1 = 0.f;
        MV_ALL()
        float gA = a0 + b0;
        float gB = a1 + b1;

        const int buf = t & 1;
        if (tid < HDIM) {
            p_sh[buf][tid] = sigm_(gA) * tanh_(gB);
        } else {
            fo_sh[buf][tid - HDIM] = make_float2(sigm_(gA), sigm_(gB));
        }
        __syncthreads();

        float  pa  = p_sh[buf][lane];
        float2 foa = fo_sh[buf][lane];
        cA = fmaf(foa.x, cA, pa);
        hA = foa.y * tanh_(cA);
        if (lane < 32) {
            float  pb  = p_sh[buf][64 + lane];
            float2 fob = fo_sh[buf][64 + lane];
            cB = fmaf(fob.x, cB, pb);
            hB = fob.y * tanh_(cB);
        }

        if (wid == 0)                    hob[(size_t)t * HDIM + lane] = hA;
        else if (wid == 1 && lane < 32)  hob[(size_t)t * HDIM + 64 + lane] = hB;

        xt = xnext;
    }
}

__global__ void __launch_bounds__(192)
__attribute__((amdgpu_waves_per_eu(1, 1)))
lstm_layer1(const float* __restrict__ xp,     // (B,T,384), bias folded
            const float* __restrict__ Whh,
            const float* __restrict__ h0,
            const float* __restrict__ c0,
            float* __restrict__ carry,        // (B,192): h[0..95], c[96..191]
            float* __restrict__ h1out,        // (B,T,96)
            int chunk, int T)
{
    const int bidx = blockIdx.x;
    const int tid  = threadIdx.x;
    const int lane = tid & 63;
    const int wid  = tid >> 6;
    const int r0   = tid;
    const int r1   = tid + 192;

    __shared__ float  p_sh[2][HDIM];
    __shared__ float2 fo_sh[2][HDIM];

    const float4* W0p = reinterpret_cast<const float4*>(Whh + r0 * HDIM);
    const float4* W1p = reinterpret_cast<const float4*>(Whh + r1 * HDIM);
    W24(WDECL)
    W24(WLOAD)
    W24(WPIN)

    float* cb = carry + bidx * 2 * HDIM;
    float hA, hB = 0.f, cA, cB = 0.f;
    if (chunk == 0) {
        hA = h0[HDIM + lane];
        cA = c0[HDIM + lane];
        if (lane < 32) { hB = h0[HDIM + 64 + lane]; cB = c0[HDIM + 64 + lane]; }
    } else {
        hA = cb[lane];
        cA = cb[HDIM + lane];
        if (lane < 32) { hB = cb[64 + lane]; cB = cb[HDIM + 64 + lane]; }
    }

    const float* xpb = xp + (size_t)bidx * T * G4;
    float*       hb1 = h1out + (size_t)bidx * T * HDIM;

    float xc0 = xpb[r0];
    float xc1 = xpb[r1];

#pragma unroll 1
    for (int t = 0; t < T; ++t) {
        float xn0 = 0.f, xn1 = 0.f;
        if (t + 1 < T) {
            const float* nx = xpb + (size_t)(t + 1) * G4;
            xn0 = nx[r0];
            xn1 = nx[r1];
        }

        float a0 = xc0, b0 = 0.f;
        float a1 = xc1, b1 = 0.f;
        MV_ALL()
        float gA = a0 + b0;
        float gB = a1 + b1;

        const int buf = t & 1;
        if (tid < HDIM) {
            p_sh[buf][tid] = sigm_(gA) * tanh_(gB);
        } else {
            fo_sh[buf][tid - HDIM] = make_float2(sigm_(gA), sigm_(gB));
        }
        __syncthreads();

        float  pa  = p_sh[buf][lane];
        float2 foa = fo_sh[buf][lane];
        cA = fmaf(foa.x, cA, pa);
        hA = foa.y * tanh_(cA);
        if (lane < 32) {
            float  pb  = p_sh[buf][64 + lane];
            float2 fob = fo_sh[buf][64 + lane];
            cB = fmaf(fob.x, cB, pb);
            hB = fob.y * tanh_(cB);
        }

        if (wid == 0)                    hb1[(size_t)t * HDIM + lane] = hA;
        else if (wid == 1 && lane < 32)  hb1[(size_t)t * HDIM + 64 + lane] = hB;

        xc0 = xn0;
        xc1 = xn1;
    }

    if (wid == 0) { cb[lane] = hA; cb[HDIM + lane] = cA; }
    else if (wid == 1 && lane < 32) { cb[64 + lane] = hB; cb[HDIM + 64 + lane] = cB; }
}

// ---------------------------------------------------------------------------
// Layer-1 input projection (parallel over timesteps), bias folded in.
// Throughput kernel: default occupancy heuristics are fine here.
// ---------------------------------------------------------------------------
__global__ __launch_bounds__(384, 1)
void xp_gemm(const float* __restrict__ hin,
             const float* __restrict__ Wih,
             const float* __restrict__ bvec,
             float* __restrict__ xp,
             int t0, int T)
{
    const int TT = 32;
    const int ntb = T / TT;
    const int b  = blockIdx.x / ntb;
    const int tb = blockIdx.x % ntb;
    const int g  = threadIdx.x;

    __shared__ __align__(16) float h_sh[TT * HDIM];

    const float4* W0p = reinterpret_cast<const float4*>(Wih + g * HDIM);
#define XDECL(n) float4 v_##n;
#define XLOAD(n) v_##n = W0p[n];
    W24(XDECL)
    W24(XLOAD)
    const float bias = bvec[g];

    const float* src = hin + ((size_t)b * LSEQ + t0 + (size_t)tb * TT) * HDIM;
    for (int i = g; i < TT * HDIM; i += G4) h_sh[i] = src[i];
    __syncthreads();

    float* dst = xp + ((size_t)b * T + (size_t)tb * TT) * G4 + g;
    for (int tt = 0; tt < TT; ++tt) {
        const float4* h4 = reinterpret_cast<const float4*>(h_sh + tt * HDIM);
        float acc0 = bias, acc1 = 0.f, acc2 = 0.f, acc3 = 0.f;
#define XFMA(n) { float4 hv = h4[n]; \
        acc0 = fmaf(v_##n.x, hv.x, acc0); acc1 = fmaf(v_##n.y, hv.y, acc1); \
        acc2 = fmaf(v_##n.z, hv.z, acc2); acc3 = fmaf(v_##n.w, hv.w, acc3); }
        W24(XFMA)
        dst[(size_t)tt * G4] = (acc0 + acc1) + (acc2 + acc3);
    }
}

// ---------------------------------------------------------------------------
// Head GEMV: out[b][t] = h1[b][t][:] . head_w + head_b
// ---------------------------------------------------------------------------
__global__ __launch_bounds__(256, 1)
void head_gemv(const float* __restrict__ h1,
               const float* __restrict__ head_w,
               const float* __restrict__ head_b,
               float* __restrict__ out,
               int chunk, int T)
{
    const int idx  = blockIdx.x * 4 + (threadIdx.x >> 6);
    const int lane = threadIdx.x & 63;
    const int b = idx / T;
    const int t = idx % T;

    const float* hp = h1 + ((size_t)b * T + t) * HDIM;
    float s = hp[lane] * head_w[lane];
    if (lane < 32) s = fmaf(hp[64 + lane], head_w[64 + lane], s);
    s += __shfl_down(s, 32);
    s += __shfl_down(s, 16);
    s += __shfl_down(s, 8);
    s += __shfl_down(s, 4);
    s += __shfl_down(s, 2);
    s += __shfl_down(s, 1);
    if (lane == 0) out[(size_t)b * LSEQ + (size_t)chunk * T + t] = s + head_b[0];
}

// ---------------------------------------------------------------------------
extern "C" void kernel_launch(void* const* d_in, const int* in_sizes, int n_in,
                              void* d_out, int out_size, void* d_ws, size_t ws_size,
                              hipStream_t stream)
{
    const float* x     = (const float*)d_in[0];
    const float* Wih0  = (const float*)d_in[1];
    const float* Whh0  = (const float*)d_in[2];
    const float* b0    = (const float*)d_in[3];
    const float* Wih1  = (const float*)d_in[4];
    const float* Whh1  = (const float*)d_in[5];
    const float* b1    = (const float*)d_in[6];
    const float* h0    = (const float*)d_in[7];
    const float* c0    = (const float*)d_in[8];
    const float* headw = (const float*)d_in[9];
    const float* headb = (const float*)d_in[10];
    float* out = (float*)d_out;

    char* ws = (char*)d_ws;
    const size_t h0bytes = (size_t)BATCH * LSEQ * HDIM * sizeof(float); // 100.7 MB

    int T = 4096;
    while (T > 512) {
        size_t need = h0bytes
                    + (size_t)T * BATCH * G4 * sizeof(float)
                    + (size_t)T * BATCH * HDIM * sizeof(float)
                    + 8192;
        if (need <= ws_size) break;
        T >>= 1;
    }

    float* h0buf = (float*)ws;
    float* xpbuf = (float*)(ws + h0bytes);
    float* h1buf = (float*)(ws + h0bytes + (size_t)T * BATCH * G4 * sizeof(float));
    float* carry = (float*)(ws + h0bytes + (size_t)T * BATCH * G4 * sizeof(float)
                               + (size_t)T * BATCH * HDIM * sizeof(float));

    lstm_layer0<<<BATCH, 192, 0, stream>>>(x, Wih0, Whh0, b0, h0, c0, h0buf);

    const int nch = LSEQ / T;
    for (int ch = 0; ch < nch; ++ch) {
        xp_gemm<<<BATCH * (T / 32), G4, 0, stream>>>(h0buf, Wih1, b1, xpbuf, ch * T, T);
        lstm_layer1<<<BATCH, 192, 0, stream>>>(xpbuf, Whh1, h0, c0, carry, h1buf, ch, T);
        head_gemv<<<BATCH * T / 4, 256, 0, stream>>>(h1buf, headw, headb, out, ch, T);
    }
}

// Round 6
// 62384.985 us; speedup vs baseline: 1.1242x; 1.1242x over previous
//
#include <hip/hip_runtime.h>
#include <hip/hip_bf16.h>

#define HDIM 96
#define G4   384
#define LSEQ 32768
#define BATCH 8

__device__ __forceinline__ float RDL(float v, int l) {
    return __uint_as_float(__builtin_amdgcn_readlane(__float_as_uint(v), l));
}
__device__ __forceinline__ float sigm_(float x) { return 1.f / (1.f + __expf(-x)); }
__device__ __forceinline__ float tanh_(float x) { return 2.f / (1.f + __expf(-2.f * x)) - 1.f; }

// 24 named float4 per thread (ONE 96-wide row) -> ~96 weight VGPRs + ~30
// working set, matching the ~130-VGPR budget the allocator actually grants.
#define W24(F) F(0) F(1) F(2) F(3) F(4) F(5) F(6) F(7) F(8) F(9) F(10) F(11) \
               F(12) F(13) F(14) F(15) F(16) F(17) F(18) F(19) F(20) F(21) F(22) F(23)
#define WDECL(n) float4 w_##n;
#define WLOAD(n) w_##n = Wp[n];
#define WPIN(n)  asm volatile("" : "+v"(w_##n.x), "+v"(w_##n.y), "+v"(w_##n.z), "+v"(w_##n.w));

// dot(w_row, h) with h broadcast via readlane; 4 accumulator chains.
#define MVA(n) { \
    float h0_ = RDL(hA, 4*n+0), h1_ = RDL(hA, 4*n+1), h2_ = RDL(hA, 4*n+2), h3_ = RDL(hA, 4*n+3); \
    a0 = fmaf(w_##n.x, h0_, a0); a1 = fmaf(w_##n.y, h1_, a1); \
    a2 = fmaf(w_##n.z, h2_, a2); a3 = fmaf(w_##n.w, h3_, a3); }
#define MVB(n) { \
    float h0_ = RDL(hB, 4*n-64), h1_ = RDL(hB, 4*n-63), h2_ = RDL(hB, 4*n-62), h3_ = RDL(hB, 4*n-61); \
    a0 = fmaf(w_##n.x, h0_, a0); a1 = fmaf(w_##n.y, h1_, a1); \
    a2 = fmaf(w_##n.z, h2_, a2); a3 = fmaf(w_##n.w, h3_, a3); }
#define MV_ALL() \
    MVA(0) MVA(1) MVA(2) MVA(3) MVA(4) MVA(5) MVA(6) MVA(7) \
    MVA(8) MVA(9) MVA(10) MVA(11) MVA(12) MVA(13) MVA(14) MVA(15) \
    MVB(16) MVB(17) MVB(18) MVB(19) MVB(20) MVB(21) MVB(22) MVB(23)

// ---------------------------------------------------------------------------
// Scan: 384 threads (6 waves), one gate row per thread (row = tid).
// Rows 0..95=i, 96..191=f, 192..287=g(tanh), 288..383=o.
// Each thread publishes its activated gate to double-buffered LDS; ONE
// barrier/step; every wave redundantly updates the c/h elements it
// broadcasts (hA=h[lane], hB=h[64+lane]) -> h never leaves registers.
// ---------------------------------------------------------------------------
__global__ void __launch_bounds__(384)
__attribute__((amdgpu_waves_per_eu(1, 2)))
lstm_layer0(const float* __restrict__ x,
            const float* __restrict__ Wih,
            const float* __restrict__ Whh,
            const float* __restrict__ bvec,
            const float* __restrict__ h0,
            const float* __restrict__ c0,
            float* __restrict__ hout)
{
    const int bidx = blockIdx.x;
    const int tid  = threadIdx.x;
    const int lane = tid & 63;
    const int wid  = tid >> 6;

    __shared__ float gates_sh[2][G4];

    const float4* Wp = reinterpret_cast<const float4*>(Whh + tid * HDIM);
    W24(WDECL)
    W24(WLOAD)
    W24(WPIN)
    const float wi = Wih[tid];
    const float bb = bvec[tid];
    const bool isTanh = (tid >= 192) && (tid < 288);

    float hA = h0[lane];
    float hB = (lane < 32) ? h0[64 + lane] : 0.f;
    float cA = c0[lane];
    float cB = (lane < 32) ? c0[64 + lane] : 0.f;

    const float* xb  = x + (size_t)bidx * LSEQ;
    float*       hob = hout + (size_t)bidx * LSEQ * HDIM;
    float xt = xb[0];

#pragma unroll 1
    for (int t = 0; t < LSEQ; ++t) {
        float xnext = (t + 1 < LSEQ) ? xb[t + 1] : 0.f;

        float a0 = fmaf(wi, xt, bb), a1 = 0.f, a2 = 0.f, a3 = 0.f;
        MV_ALL()
        float g = (a0 + a1) + (a2 + a3);

        const int buf = t & 1;
        {
            float arg = isTanh ? (-2.f * g) : (-g);
            float r = 1.f / (1.f + __expf(arg));
            gates_sh[buf][tid] = isTanh ? (2.f * r - 1.f) : r;
        }
        __syncthreads();

        float si = gates_sh[buf][lane];
        float sf = gates_sh[buf][96 + lane];
        float tg = gates_sh[buf][192 + lane];
        float so = gates_sh[buf][288 + lane];
        cA = fmaf(sf, cA, si * tg);
        hA = so * tanh_(cA);
        if (lane < 32) {
            float si2 = gates_sh[buf][64 + lane];
            float sf2 = gates_sh[buf][160 + lane];
            float tg2 = gates_sh[buf][256 + lane];
            float so2 = gates_sh[buf][352 + lane];
            cB = fmaf(sf2, cB, si2 * tg2);
            hB = so2 * tanh_(cB);
        }

        if (wid == 0)                    hob[(size_t)t * HDIM + lane] = hA;
        else if (wid == 1 && lane < 32)  hob[(size_t)t * HDIM + 64 + lane] = hB;

        xt = xnext;
    }
}

__global__ void __launch_bounds__(384)
__attribute__((amdgpu_waves_per_eu(1, 2)))
lstm_layer1(const float* __restrict__ xp,     // (B,T,384), bias folded
            const float* __restrict__ Whh,
            const float* __restrict__ h0,
            const float* __restrict__ c0,
            float* __restrict__ carry,        // (B,192): h[0..95], c[96..191]
            float* __restrict__ h1out,        // (B,T,96)
            int chunk, int T)
{
    const int bidx = blockIdx.x;
    const int tid  = threadIdx.x;
    const int lane = tid & 63;
    const int wid  = tid >> 6;

    __shared__ float gates_sh[2][G4];

    const float4* Wp = reinterpret_cast<const float4*>(Whh + tid * HDIM);
    W24(WDECL)
    W24(WLOAD)
    W24(WPIN)
    const bool isTanh = (tid >= 192) && (tid < 288);

    float* cb = carry + bidx * 2 * HDIM;
    float hA, hB = 0.f, cA, cB = 0.f;
    if (chunk == 0) {
        hA = h0[HDIM + lane];
        cA = c0[HDIM + lane];
        if (lane < 32) { hB = h0[HDIM + 64 + lane]; cB = c0[HDIM + 64 + lane]; }
    } else {
        hA = cb[lane];
        cA = cb[HDIM + lane];
        if (lane < 32) { hB = cb[64 + lane]; cB = cb[HDIM + 64 + lane]; }
    }

    const float* xpb = xp + (size_t)bidx * T * G4;
    float*       hb1 = h1out + (size_t)bidx * T * HDIM;

    float xc = xpb[tid];

#pragma unroll 1
    for (int t = 0; t < T; ++t) {
        float xn = (t + 1 < T) ? xpb[(size_t)(t + 1) * G4 + tid] : 0.f;

        float a0 = xc, a1 = 0.f, a2 = 0.f, a3 = 0.f;
        MV_ALL()
        float g = (a0 + a1) + (a2 + a3);

        const int buf = t & 1;
        {
            float arg = isTanh ? (-2.f * g) : (-g);
            float r = 1.f / (1.f + __expf(arg));
            gates_sh[buf][tid] = isTanh ? (2.f * r - 1.f) : r;
        }
        __syncthreads();

        float si = gates_sh[buf][lane];
        float sf = gates_sh[buf][96 + lane];
        float tg = gates_sh[buf][192 + lane];
        float so = gates_sh[buf][288 + lane];
        cA = fmaf(sf, cA, si * tg);
        hA = so * tanh_(cA);
        if (lane < 32) {
            float si2 = gates_sh[buf][64 + lane];
            float sf2 = gates_sh[buf][160 + lane];
            float tg2 = gates_sh[buf][256 + lane];
            float so2 = gates_sh[buf][352 + lane];
            cB = fmaf(sf2, cB, si2 * tg2);
            hB = so2 * tanh_(cB);
        }

        if (wid == 0)                    hb1[(size_t)t * HDIM + lane] = hA;
        else if (wid == 1 && lane < 32)  hb1[(size_t)t * HDIM + 64 + lane] = hB;

        xc = xn;
    }

    if (wid == 0) { cb[lane] = hA; cb[HDIM + lane] = cA; }
    else if (wid == 1 && lane < 32) { cb[64 + lane] = hB; cb[HDIM + 64 + lane] = cB; }
}

// ---------------------------------------------------------------------------
// Layer-1 input projection (parallel over timesteps), bias folded in.
// ---------------------------------------------------------------------------
__global__ __launch_bounds__(384, 1)
void xp_gemm(const float* __restrict__ hin,
             const float* __restrict__ Wih,
             const float* __restrict__ bvec,
             float* __restrict__ xp,
             int t0, int T)
{
    const int TT = 32;
    const int ntb = T / TT;
    const int b  = blockIdx.x / ntb;
    const int tb = blockIdx.x % ntb;
    const int g  = threadIdx.x;

    __shared__ __align__(16) float h_sh[TT * HDIM];

    const float4* W0p = reinterpret_cast<const float4*>(Wih + g * HDIM);
#define XDECL(n) float4 v_##n;
#define XLOAD(n) v_##n = W0p[n];
    W24(XDECL)
    W24(XLOAD)
    const float bias = bvec[g];

    const float* src = hin + ((size_t)b * LSEQ + t0 + (size_t)tb * TT) * HDIM;
    for (int i = g; i < TT * HDIM; i += G4) h_sh[i] = src[i];
    __syncthreads();

    float* dst = xp + ((size_t)b * T + (size_t)tb * TT) * G4 + g;
    for (int tt = 0; tt < TT; ++tt) {
        const float4* h4 = reinterpret_cast<const float4*>(h_sh + tt * HDIM);
        float acc0 = bias, acc1 = 0.f, acc2 = 0.f, acc3 = 0.f;
#define XFMA(n) { float4 hv = h4[n]; \
        acc0 = fmaf(v_##n.x, hv.x, acc0); acc1 = fmaf(v_##n.y, hv.y, acc1); \
        acc2 = fmaf(v_##n.z, hv.z, acc2); acc3 = fmaf(v_##n.w, hv.w, acc3); }
        W24(XFMA)
        dst[(size_t)tt * G4] = (acc0 + acc1) + (acc2 + acc3);
    }
}

// ---------------------------------------------------------------------------
// Head GEMV: out[b][t] = h1[b][t][:] . head_w + head_b
// ---------------------------------------------------------------------------
__global__ __launch_bounds__(256, 1)
void head_gemv(const float* __restrict__ h1,
               const float* __restrict__ head_w,
               const float* __restrict__ head_b,
               float* __restrict__ out,
               int chunk, int T)
{
    const int idx  = blockIdx.x * 4 + (threadIdx.x >> 6);
    const int lane = threadIdx.x & 63;
    const int b = idx / T;
    const int t = idx % T;

    const float* hp = h1 + ((size_t)b * T + t) * HDIM;
    float s = hp[lane] * head_w[lane];
    if (lane < 32) s = fmaf(hp[64 + lane], head_w[64 + lane], s);
    s += __shfl_down(s, 32);
    s += __shfl_down(s, 16);
    s += __shfl_down(s, 8);
    s += __shfl_down(s, 4);
    s += __shfl_down(s, 2);
    s += __shfl_down(s, 1);
    if (lane == 0) out[(size_t)b * LSEQ + (size_t)chunk * T + t] = s + head_b[0];
}

// ---------------------------------------------------------------------------
extern "C" void kernel_launch(void* const* d_in, const int* in_sizes, int n_in,
                              void* d_out, int out_size, void* d_ws, size_t ws_size,
                              hipStream_t stream)
{
    const float* x     = (const float*)d_in[0];
    const float* Wih0  = (const float*)d_in[1];
    const float* Whh0  = (const float*)d_in[2];
    const float* b0    = (const float*)d_in[3];
    const float* Wih1  = (const float*)d_in[4];
    const float* Whh1  = (const float*)d_in[5];
    const float* b1    = (const float*)d_in[6];
    const float* h0    = (const float*)d_in[7];
    const float* c0    = (const float*)d_in[8];
    const float* headw = (const float*)d_in[9];
    const float* headb = (const float*)d_in[10];
    float* out = (float*)d_out;

    char* ws = (char*)d_ws;
    const size_t h0bytes = (size_t)BATCH * LSEQ * HDIM * sizeof(float); // 100.7 MB

    int T = 4096;
    while (T > 512) {
        size_t need = h0bytes
                    + (size_t)T * BATCH * G4 * sizeof(float)
                    + (size_t)T * BATCH * HDIM * sizeof(float)
                    + 8192;
        if (need <= ws_size) break;
        T >>= 1;
    }

    float* h0buf = (float*)ws;
    float* xpbuf = (float*)(ws + h0bytes);
    float* h1buf = (float*)(ws + h0bytes + (size_t)T * BATCH * G4 * sizeof(float));
    float* carry = (float*)(ws + h0bytes + (size_t)T * BATCH * G4 * sizeof(float)
                               + (size_t)T * BATCH * HDIM * sizeof(float));

    lstm_layer0<<<BATCH, G4, 0, stream>>>(x, Wih0, Whh0, b0, h0, c0, h0buf);

    const int nch = LSEQ / T;
    for (int ch = 0; ch < nch; ++ch) {
        xp_gemm<<<BATCH * (T / 32), G4, 0, stream>>>(h0buf, Wih1, b1, xpbuf, ch * T, T);
        lstm_layer1<<<BATCH, G4, 0, stream>>>(xpbuf, Whh1, h0, c0, carry, h1buf, ch, T);
        head_gemv<<<BATCH * T / 4, 256, 0, stream>>>(h1buf, headw, headb, out, ch, T);
    }
}